// Round 18
// baseline (295.934 us; speedup 1.0000x reference)
//
#include <hip/hip_runtime.h>
#include <hip/hip_bf16.h>
#include <math.h>

// Problem constants
#define NB   1024   // batch
#define NT   60     // time steps
#define NC   10     // in channels
#define NDM  256    // d_model
#define NH   16     // heads
#define NDH  16     // per-head value dim
#define NA   13     // num attention queries
#define NM   208    // NA*NH
#define NMO  128    // MLP out

// weff6 row: 128 groups x 32 floats (128 B aligned); group g = d-pair (2g, 2g+1),
// slot dl*13+ak for dl in {0,1}; slots 26..31 pad. Row = 4096 floats.
#define WROW6 4096

// vgT layout (QUAD-INTERLEAVED): element (b, d, t) lives at
// b*BSTRIDE + (d>>2)*256 + t*4 + (d&3). Lane tk's float4 load at q*256+tk*4
// yields v[4q..4q+3][tk]; a wave-load spans 1KB contiguous (fully coalesced).
#define BSTRIDE (NDM*64)

// Workspace layout (floats)
#define OFF_WEFF  0
#define N_WEFF    (NH*14*WROW6)                // 917,504
#define OFF_BEFF  (OFF_WEFF + N_WEFF)
#define N_BEFF    (NM*NH*NA)                   // 43,264
#define OFF_VGT   (OFF_BEFF + N_BEFF)
#define N_VGT     (NB*NDM*64)                  // 16,777,216
#define OFF_ATT   (OFF_VGT + N_VGT)
#define N_ATT     (NM*NB*NDH)                  // 3,407,872

#define LDS_FENCE() __asm__ __volatile__("s_waitcnt lgkmcnt(0)" ::: "memory")

// ---------------- K0: weff6[hk][mi][g][32], m = 13*hk+mi
__global__ void ltae_weff(const float* __restrict__ Q, const float* __restrict__ Wk,
                          const float* __restrict__ bk, float* __restrict__ weff6,
                          float* __restrict__ beff2) {
    int blk = blockIdx.x;            // hk*14 + mi
    int hk = blk / 14, mi = blk - hk*14;
    int m  = hk*13 + mi;
    int mc = m > 207 ? 207 : m;      // slot (15,13) provably never read
    int d = threadIdx.x;
    float q0 = Q[mc*4+0], q1 = Q[mc*4+1], q2 = Q[mc*4+2], q3 = Q[mc*4+3];
    int g = d >> 1, dl = d & 1;
    size_t base = (size_t)blk*WROW6 + g*32 + dl*13;
#pragma unroll
    for (int ak = 0; ak < NA; ++ak) {
        int e = (ak*16 + hk)*4;
        float w = q0*Wk[(size_t)(e+0)*NDM + d] + q1*Wk[(size_t)(e+1)*NDM + d]
                + q2*Wk[(size_t)(e+2)*NDM + d] + q3*Wk[(size_t)(e+3)*NDM + d];
        weff6[base + ak] = w;
    }
    if (dl == 1) {               // zero the 6 pad slots of this group
#pragma unroll
        for (int p = 26; p < 32; ++p) weff6[(size_t)blk*WROW6 + g*32 + p] = 0.f;
    }
    if (d < NA && m <= 207) {
        int e = (d*16 + hk)*4;
        beff2[(m*16 + hk)*NA + d] = q0*bk[e] + q1*bk[e+1] + q2*bk[e+2] + q3*bk[e+3];
    }
}

// ---------------- K1: conv 1x1 + GroupNorm -> vgT quad-interleaved
#define VT_S 66
#define K1_LDS_BYTES ((NDM*VT_S + NT*NC)*4)

__launch_bounds__(1024, 8)
__global__ void ltae_convgn(const float* __restrict__ x, const float* __restrict__ Wc,
                            const float* __restrict__ bc, const float* __restrict__ gnw,
                            const float* __restrict__ gnb, float* __restrict__ vgT) {
    extern __shared__ float smem[];
    float* Vt = smem;
    float* xs = smem + NDM*VT_S;
    int b = blockIdx.x, tid = threadIdx.x;
    if (tid < NT*NC) xs[tid] = x[(size_t)b*NT*NC + tid];
    __syncthreads();
    {
        int d = tid >> 2, q = tid & 3;   // wave = 16 d = one GN group
        float wc[NC];
#pragma unroll
        for (int c = 0; c < NC; ++c) wc[c] = Wc[d*NC + c];
        float bcv = bc[d];
        float h[15];
        float s1 = 0.f, s2 = 0.f;
#pragma unroll
        for (int k = 0; k < 15; ++k) {
            int t = 15*q + k;
            float a = bcv;
#pragma unroll
            for (int c = 0; c < NC; ++c) a = fmaf(xs[t*NC + c], wc[c], a);
            h[k] = a; s1 += a; s2 += a*a;
        }
#pragma unroll
        for (int off = 1; off < 64; off <<= 1) {
            s1 += __shfl_xor(s1, off);
            s2 += __shfl_xor(s2, off);
        }
        float mean = s1 * (1.f/960.f);
        float var  = s2 * (1.f/960.f) - mean*mean;
        float rstd = rsqrtf(var + 1e-5f);
        float g = gnw[d], bb = gnb[d];
#pragma unroll
        for (int k = 0; k < 15; ++k)
            Vt[d*VT_S + 15*q + k] = (h[k]-mean)*rstd*g + bb;
    }
    __syncthreads();
    // quad-interleaved store: float4 at (q,t) = rows 4q..4q+3, column t;
    // addr = i*4 -> consecutive threads write consecutive 16B -> coalesced.
    float* vb = vgT + (size_t)b*BSTRIDE;
    for (int i = tid; i < NDM*16; i += 1024) {
        int qd = i >> 6, t = i & 63;
        float4 o;
        if (t < NT) {
            o.x = Vt[(4*qd+0)*VT_S + t];
            o.y = Vt[(4*qd+1)*VT_S + t];
            o.z = Vt[(4*qd+2)*VT_S + t];
            o.w = Vt[(4*qd+3)*VT_S + t];
        } else {
            o.x = o.y = o.z = o.w = 0.f;
        }
        *(float4*)&vb[(size_t)i*4] = o;
    }
}

// ---------------- K2: scrambled attention; JB=1, quad v, UNROLL-2 pass A.
// R13/R15/R17 controlled trio falsified all v-load hypotheses (count,
// coalescing, prefetch depth): identical 165us / VALUBusy 49%. Remaining
// unisolated stall: SCALAR weight latency — ~19 resident waves stream 19
// DISTINCT 16KB rows, scalar-L1 thrashes, so each iteration's s_load cluster
// is a ~200-300cy lgkm drain against only 416 FMA cycles (retro-explains
// R7's collapse when the stream doubled, and R11's neutral row-sharing:
// sharing fixes bandwidth, not latency). R18: #pragma unroll 2 — the
// scheduler hoists both iterations' s_load clusters and emits fine-grained
// lgkmcnt(N) waits, halving exposed lgkm-drain events per FMA. One-pragma
// diff; math/layout/geometry identical.
__launch_bounds__(128, 8)
__global__ void ltae_attn(const float* __restrict__ vgT, const float* __restrict__ weff6,
                          const float* __restrict__ beff2, float* __restrict__ attout) {
    __shared__ float wbuf[2*784];        // 6,272 B
    int p = blockIdx.x;                  // 8192 = 8 xcd * 128 b * 8 hkp
    int xcd = p & 7, idx = p >> 3;
    int b   = xcd * 128 + (idx >> 3);    // bijective: 8*128*8 = 8192
    int hkp = idx & 7;                   // block's hk pair
    int tid = threadIdx.x;
    int wid = tid >> 6, lane = tid & 63;
    int hk = __builtin_amdgcn_readfirstlane(hkp*2 + wid);  // wave-uniform scalar
    int tk = lane;
    int mi0   = (13*b) >> 10;                            // block-uniform scalar
    int rstar = ((mi0+1) << 10) - 13*b;                  // pass B iff rstar < 13
    const float* __restrict__ wrow = weff6 + (size_t)(hk*14 + mi0)*WROW6;
    const float4* __restrict__ vX4 = (const float4*)(vgT + (size_t)b*BSTRIDE) + tk;
    float* myC = wbuf + wid*784;

    float acc[13];
#pragma unroll
    for (int j = 0; j < 13; ++j) acc[j] = 0.f;

    // ---- pass A: prologue loads quads 0,1; rotation keeps next pair in
    // flight; unroll 2 lets the scheduler batch two iterations' s_load
    // clusters -> one exposed lgkm drain per 832 FMA-cycles instead of 416.
    float4 A = vX4[0];
    float4 B = vX4[64];
#pragma unroll 2
    for (int gg = 0; gg < 32; ++gg) {
        const float* wg0 = wrow + (size_t)(4*gg)*32;     // uniform -> s_load
        const float* wg1 = wg0 + 32;
        const float* wg2 = wg0 + 64;
        const float* wg3 = wg0 + 96;
        float4 An = vX4[(2*gg+2)*64];    // gg=31: overread into attout, unused
        float4 Bn = vX4[(2*gg+3)*64];
#pragma unroll
        for (int ak = 0; ak < 13; ++ak)
            acc[ak] = fmaf(A.y, wg0[13+ak], fmaf(A.x, wg0[ak], acc[ak]));
#pragma unroll
        for (int ak = 0; ak < 13; ++ak)
            acc[ak] = fmaf(A.w, wg1[13+ak], fmaf(A.z, wg1[ak], acc[ak]));
#pragma unroll
        for (int ak = 0; ak < 13; ++ak)
            acc[ak] = fmaf(B.y, wg2[13+ak], fmaf(B.x, wg2[ak], acc[ak]));
#pragma unroll
        for (int ak = 0; ak < 13; ++ak)
            acc[ak] = fmaf(B.w, wg3[13+ak], fmaf(B.z, wg3[ak], acc[ak]));
        A = An; B = Bn;
    }

    // ---- pass B (rare): rows r >= rstar use weight row mi0+1; float2 v
    // (d-pair 2g,2g+1 adjacent within quad g>>1 at sub-offset (g&1)*2).
    if (rstar < 13) {
        int ustar = 60*rstar;
        int tstar = (ustar >= 1) ? (ustar/13) : -1;
        if (tk == tstar) {
#pragma unroll
            for (int j = 0; j < 13; ++j) myC[j] = acc[j];
        }
        LDS_FENCE();
        if (tk >= tstar) {
#pragma unroll
            for (int j = 0; j < 13; ++j) acc[j] = 0.f;
            const float* __restrict__ wrow2 = weff6 + (size_t)(hk*14 + mi0 + 1)*WROW6;
            const float* __restrict__ vB = vgT + (size_t)b*BSTRIDE + tk*4;
#pragma unroll 1
            for (int g = 0; g < 128; ++g) {
                const float* wg = wrow2 + g*32;
                float2 v01 = *(const float2*)&vB[(g>>1)*256 + (g&1)*2];
#pragma unroll
                for (int ak = 0; ak < 13; ++ak)
                    acc[ak] = fmaf(v01.y, wg[13+ak], fmaf(v01.x, wg[ak], acc[ak]));
            }
        }
        if (tk == tstar) {
#pragma unroll
            for (int j = 0; j < 13; ++j)
                if (13*tk + j < ustar) acc[j] = myC[j];
        }
        LDS_FENCE();
    }

    // ---- softmax + AV (single b, single hk); exact R2 row structure.
    int dh = lane >> 2, cc = lane & 3;
    int hb13 = (hk*1024 + b)*13;
    if (tk < NT) {
#pragma unroll
        for (int j = 0; j < 13; ++j) myC[13*tk + j] = acc[j];
    }
    LDS_FENCE();
    // vreg: v[b][d = hk*16+dh][t = cc+4j] in quad layout:
    // (d>>2) = hk*4 + (dh>>2), sub = dh&3
    float vreg[15];
#pragma unroll
    for (int j = 0; j < 15; ++j)
        vreg[j] = vgT[(size_t)b*BSTRIDE + (size_t)(hk*4 + (dh>>2))*256
                      + (cc + 4*j)*4 + (dh&3)];
#pragma unroll 1
    for (int r = 0; r < 13; ++r) {
        int n = hb13 + r;
        int m = n >> 10;                         // exact variant for this row
        int brow = (m*16 + hk)*13;
        float logit = -1e30f;
        if (lane < NT) {
            int u  = r*60 + lane;
            int ak = u % 13;
            logit = (myC[u] + beff2[brow + ak]) * 0.5f;
        }
        float mx = logit;
#pragma unroll
        for (int off = 32; off; off >>= 1) mx = fmaxf(mx, __shfl_xor(mx, off));
        float e = (lane < NT) ? __expf(logit - mx) : 0.f;
        float s = e;
#pragma unroll
        for (int off = 32; off; off >>= 1) s += __shfl_xor(s, off);
        float attn = e / s;
        if (lane < NT) myC[r*60 + lane] = attn;  // same-wave in-order LDS
        LDS_FENCE();
        float a = 0.f;
#pragma unroll
        for (int j = 0; j < 15; ++j)
            a = fmaf(myC[r*60 + cc + 4*j], vreg[j], a);
        a += __shfl_xor(a, 1);
        a += __shfl_xor(a, 2);
        if (cc == 0) attout[(size_t)n*NDH + dh] = a;
    }
}

// ---------------- K3: MLP + BN(eval) + ReLU + GroupNorm(16,128); 16 rows/block.
// R9-verified WIN (~75us): j = tid>>3, sl = tid&7 -> 8 lanes SHARE each W1
// row (float4 wave-load = 2 cachelines, was 64). f stride 260 keeps the 8
// distinct f[sl] reads conflict-free. GN octet at lane stride 8 -> shuffle
// offsets {8,16,32}. Math identical to original.
#define FS 260
__launch_bounds__(1024)
__global__ void ltae_mlp(const float* __restrict__ attout, const float* __restrict__ W1,
                         const float* __restrict__ b1, const float* __restrict__ bnw,
                         const float* __restrict__ bnb, const float* __restrict__ bnrm,
                         const float* __restrict__ bnrv, const float* __restrict__ gow,
                         const float* __restrict__ gob, float* __restrict__ out) {
    __shared__ float f[16*FS];   // 16,640 B
    int tid = threadIdx.x;
    int sl  = tid & 7;           // sample slot 0..7 (8 lanes share a W1 row)
    int j   = tid >> 3;          // output channel 0..127
    int base = blockIdx.x << 4;  // 16 sids per block; sid = a2*1024 + b2
    for (int k = tid; k < 16*NDM; k += 1024) {
        int s = k >> 8, c = k & 255;
        int sid2 = base + s;
        int aa = sid2 >> 10, bb = sid2 & 1023;
        int h2 = c >> 4, dhh = c & 15;
        f[s*FS + c] = attout[((size_t)((aa*16 + h2)*1024 + bb))*NDH + dhh];
    }
    __syncthreads();
    const float* fr0 = f + sl*FS;
    const float* fr1 = f + (sl+8)*FS;
    const float* w   = &W1[(size_t)j*NDM];
    float bj = b1[j];
    float acc0 = bj, acc1 = bj;
    for (int c = 0; c < NDM; c += 4) {
        float4 wv = *(const float4*)&w[c];      // 8 lanes/addr -> 2 lines/wave
        float4 f0 = *(const float4*)&fr0[c];    // 16B-aligned (FS*4 % 16 == 0)
        float4 f1 = *(const float4*)&fr1[c];
        acc0 += wv.x*f0.x + wv.y*f0.y + wv.z*f0.z + wv.w*f0.w;
        acc1 += wv.x*f1.x + wv.y*f1.y + wv.z*f1.z + wv.w*f1.w;
    }
    float rs = rsqrtf(bnrv[j] + 1e-5f);
    float sc = rs * bnw[j];
    float sh = bnb[j] - bnrm[j]*sc;
    float y0 = fmaxf(acc0*sc + sh, 0.f);
    float y1 = fmaxf(acc1*sc + sh, 0.f);
    float a1 = y0, b1s = y0*y0, a2 = y1, b2s = y1*y1;
#pragma unroll
    for (int off = 8; off < 64; off <<= 1) {    // GN octet at lane stride 8
        a1  += __shfl_xor(a1, off);
        b1s += __shfl_xor(b1s, off);
        a2  += __shfl_xor(a2, off);
        b2s += __shfl_xor(b2s, off);
    }
    float gw = gow[j], gb = gob[j];
    {
        float mean = a1 * 0.125f;
        float var  = b1s * 0.125f - mean*mean;
        float o = (y0 - mean) * rsqrtf(var + 1e-5f) * gw + gb;
        int sid = base + sl, aa = sid >> 10, bb = sid & 1023;
        out[((size_t)bb*NA + aa)*NMO + j] = o;
    }
    {
        float mean = a2 * 0.125f;
        float var  = b2s * 0.125f - mean*mean;
        float o = (y1 - mean) * rsqrtf(var + 1e-5f) * gw + gb;
        int sid = base + sl + 8, aa = sid >> 10, bb = sid & 1023;
        out[((size_t)bb*NA + aa)*NMO + j] = o;
    }
}

extern "C" void kernel_launch(void* const* d_in, const int* in_sizes, int n_in,
                              void* d_out, int out_size, void* d_ws, size_t ws_size,
                              hipStream_t stream) {
    const float* x    = (const float*)d_in[0];
    const float* Wc   = (const float*)d_in[1];
    const float* bc   = (const float*)d_in[2];
    const float* gnw  = (const float*)d_in[3];
    const float* gnb  = (const float*)d_in[4];
    const float* Q    = (const float*)d_in[5];
    const float* Wk   = (const float*)d_in[6];
    const float* bk   = (const float*)d_in[7];
    const float* W1   = (const float*)d_in[8];
    const float* b1   = (const float*)d_in[9];
    const float* bnw  = (const float*)d_in[10];
    const float* bnb  = (const float*)d_in[11];
    const float* bnrm = (const float*)d_in[12];
    const float* bnrv = (const float*)d_in[13];
    const float* gow  = (const float*)d_in[14];
    const float* gob  = (const float*)d_in[15];

    float* ws     = (float*)d_ws;
    float* weff6  = ws + OFF_WEFF;
    float* beff2  = ws + OFF_BEFF;
    float* vgT    = ws + OFF_VGT;
    float* attout = ws + OFF_ATT;
    float* outp   = (float*)d_out;

    hipLaunchKernelGGL(ltae_weff, dim3(NH*14), dim3(256), 0, stream, Q, Wk, bk, weff6, beff2);
    hipFuncSetAttribute((const void*)ltae_convgn,
                        hipFuncAttributeMaxDynamicSharedMemorySize, K1_LDS_BYTES);
    hipLaunchKernelGGL(ltae_convgn, dim3(NB), dim3(1024), K1_LDS_BYTES, stream,
                       x, Wc, bc, gnw, gnb, vgT);
    hipLaunchKernelGGL(ltae_attn, dim3(8192), dim3(128), 0, stream,
                       vgT, weff6, beff2, attout);
    hipLaunchKernelGGL(ltae_mlp, dim3(NA*NB/16), dim3(1024), 0, stream,
                       attout, W1, b1, bnw, bnb, bnrm, bnrv, gow, gob, outp);
}

// Round 19
// 292.569 us; speedup vs baseline: 1.0115x; 1.0115x over previous
//
#include <hip/hip_runtime.h>
#include <hip/hip_bf16.h>
#include <math.h>

// Problem constants
#define NB   1024   // batch
#define NT   60     // time steps
#define NC   10     // in channels
#define NDM  256    // d_model
#define NH   16     // heads
#define NDH  16     // per-head value dim
#define NA   13     // num attention queries
#define NM   208    // NA*NH
#define NMO  128    // MLP out

// weff6 row: 128 groups x 32 floats (128 B aligned); group g = d-pair (2g, 2g+1),
// slot dl*13+ak for dl in {0,1}; slots 26..31 pad. Row = 4096 floats.
#define WROW6 4096

// vgT layout (QUAD-INTERLEAVED): element (b, d, t) lives at
// b*BSTRIDE + (d>>2)*256 + t*4 + (d&3). Lane tk's float4 load at q*256+tk*4
// yields v[4q..4q+3][tk]; a wave-load spans 1KB contiguous (fully coalesced).
#define BSTRIDE (NDM*64)

// Workspace layout (floats)
#define OFF_WEFF  0
#define N_WEFF    (NH*14*WROW6)                // 917,504
#define OFF_BEFF  (OFF_WEFF + N_WEFF)
#define N_BEFF    (NM*NH*NA)                   // 43,264
#define OFF_VGT   (OFF_BEFF + N_BEFF)
#define N_VGT     (NB*NDM*64)                  // 16,777,216
#define OFF_ATT   (OFF_VGT + N_VGT)
#define N_ATT     (NM*NB*NDH)                  // 3,407,872

#define LDS_FENCE() __asm__ __volatile__("s_waitcnt lgkmcnt(0)" ::: "memory")

// ---------------- K0: weff6[hk][mi][g][32], m = 13*hk+mi
__global__ void ltae_weff(const float* __restrict__ Q, const float* __restrict__ Wk,
                          const float* __restrict__ bk, float* __restrict__ weff6,
                          float* __restrict__ beff2) {
    int blk = blockIdx.x;            // hk*14 + mi
    int hk = blk / 14, mi = blk - hk*14;
    int m  = hk*13 + mi;
    int mc = m > 207 ? 207 : m;      // slot (15,13) provably never read
    int d = threadIdx.x;
    float q0 = Q[mc*4+0], q1 = Q[mc*4+1], q2 = Q[mc*4+2], q3 = Q[mc*4+3];
    int g = d >> 1, dl = d & 1;
    size_t base = (size_t)blk*WROW6 + g*32 + dl*13;
#pragma unroll
    for (int ak = 0; ak < NA; ++ak) {
        int e = (ak*16 + hk)*4;
        float w = q0*Wk[(size_t)(e+0)*NDM + d] + q1*Wk[(size_t)(e+1)*NDM + d]
                + q2*Wk[(size_t)(e+2)*NDM + d] + q3*Wk[(size_t)(e+3)*NDM + d];
        weff6[base + ak] = w;
    }
    if (dl == 1) {               // zero the 6 pad slots of this group
#pragma unroll
        for (int p = 26; p < 32; ++p) weff6[(size_t)blk*WROW6 + g*32 + p] = 0.f;
    }
    if (d < NA && m <= 207) {
        int e = (d*16 + hk)*4;
        beff2[(m*16 + hk)*NA + d] = q0*bk[e] + q1*bk[e+1] + q2*bk[e+2] + q3*bk[e+3];
    }
}

// ---------------- K1: conv 1x1 + GroupNorm -> vgT quad-interleaved
#define VT_S 66
#define K1_LDS_BYTES ((NDM*VT_S + NT*NC)*4)

__launch_bounds__(1024, 8)
__global__ void ltae_convgn(const float* __restrict__ x, const float* __restrict__ Wc,
                            const float* __restrict__ bc, const float* __restrict__ gnw,
                            const float* __restrict__ gnb, float* __restrict__ vgT) {
    extern __shared__ float smem[];
    float* Vt = smem;
    float* xs = smem + NDM*VT_S;
    int b = blockIdx.x, tid = threadIdx.x;
    if (tid < NT*NC) xs[tid] = x[(size_t)b*NT*NC + tid];
    __syncthreads();
    {
        int d = tid >> 2, q = tid & 3;   // wave = 16 d = one GN group
        float wc[NC];
#pragma unroll
        for (int c = 0; c < NC; ++c) wc[c] = Wc[d*NC + c];
        float bcv = bc[d];
        float h[15];
        float s1 = 0.f, s2 = 0.f;
#pragma unroll
        for (int k = 0; k < 15; ++k) {
            int t = 15*q + k;
            float a = bcv;
#pragma unroll
            for (int c = 0; c < NC; ++c) a = fmaf(xs[t*NC + c], wc[c], a);
            h[k] = a; s1 += a; s2 += a*a;
        }
#pragma unroll
        for (int off = 1; off < 64; off <<= 1) {
            s1 += __shfl_xor(s1, off);
            s2 += __shfl_xor(s2, off);
        }
        float mean = s1 * (1.f/960.f);
        float var  = s2 * (1.f/960.f) - mean*mean;
        float rstd = rsqrtf(var + 1e-5f);
        float g = gnw[d], bb = gnb[d];
#pragma unroll
        for (int k = 0; k < 15; ++k)
            Vt[d*VT_S + 15*q + k] = (h[k]-mean)*rstd*g + bb;
    }
    __syncthreads();
    // quad-interleaved store: float4 at (q,t) = rows 4q..4q+3, column t;
    // addr = i*4 -> consecutive threads write consecutive 16B -> coalesced.
    float* vb = vgT + (size_t)b*BSTRIDE;
    for (int i = tid; i < NDM*16; i += 1024) {
        int qd = i >> 6, t = i & 63;
        float4 o;
        if (t < NT) {
            o.x = Vt[(4*qd+0)*VT_S + t];
            o.y = Vt[(4*qd+1)*VT_S + t];
            o.z = Vt[(4*qd+2)*VT_S + t];
            o.w = Vt[(4*qd+3)*VT_S + t];
        } else {
            o.x = o.y = o.z = o.w = 0.f;
        }
        *(float4*)&vb[(size_t)i*4] = o;
    }
}

// ---------------- K2: scrambled attention; JB=1, quad v, PHASE-BATCHED epilogue.
// R15/R17/R18 nulls prove pass A's loads are fully pipelined (count,
// coalescing, prefetch depth, scalar batching all neutral at 164-165us,
// VALUBusy 50%). Remaining latency: the EPILOGUE — 13 rows x ~500-700cy
// serial chain (LDS read -> beff2 L2 load -> 6-deep shuffle-max -> exp ->
// 6-deep shuffle-sum -> div -> LDS write -> AV) ~= 40% of wave time, pure
// dependency latency that ~5 resident waves/SIMD cannot cover.
// R19: phase-batch the 13 rows (R3's structure). R3 regressed from VGPR
// pressure at JB=2 (52 VGPR, occ 39->28); at JB=1 we start from 20 VGPR —
// lg[13] (reused as ex) + vreg[15] peaks ~48 < 64 cap at 8 waves/SIMD.
// 13 independent shuffle chains now pipeline instead of serializing.
__launch_bounds__(128, 8)
__global__ void ltae_attn(const float* __restrict__ vgT, const float* __restrict__ weff6,
                          const float* __restrict__ beff2, float* __restrict__ attout) {
    __shared__ float wbuf[2*784];        // 6,272 B
    int p = blockIdx.x;                  // 8192 = 8 xcd * 128 b * 8 hkp
    int xcd = p & 7, idx = p >> 3;
    int b   = xcd * 128 + (idx >> 3);    // bijective: 8*128*8 = 8192
    int hkp = idx & 7;                   // block's hk pair
    int tid = threadIdx.x;
    int wid = tid >> 6, lane = tid & 63;
    int hk = __builtin_amdgcn_readfirstlane(hkp*2 + wid);  // wave-uniform scalar
    int tk = lane;
    int mi0   = (13*b) >> 10;                            // block-uniform scalar
    int rstar = ((mi0+1) << 10) - 13*b;                  // pass B iff rstar < 13
    const float* __restrict__ wrow = weff6 + (size_t)(hk*14 + mi0)*WROW6;
    const float4* __restrict__ vX4 = (const float4*)(vgT + (size_t)b*BSTRIDE) + tk;
    float* myC = wbuf + wid*784;

    float acc[13];
#pragma unroll
    for (int j = 0; j < 13; ++j) acc[j] = 0.f;

    // ---- pass A: prologue loads quads 0,1; rotation keeps next pair in
    // flight; unroll 2 batches two iterations' s_load clusters (R18).
    float4 A = vX4[0];
    float4 B = vX4[64];
#pragma unroll 2
    for (int gg = 0; gg < 32; ++gg) {
        const float* wg0 = wrow + (size_t)(4*gg)*32;     // uniform -> s_load
        const float* wg1 = wg0 + 32;
        const float* wg2 = wg0 + 64;
        const float* wg3 = wg0 + 96;
        float4 An = vX4[(2*gg+2)*64];    // gg=31: overread into attout, unused
        float4 Bn = vX4[(2*gg+3)*64];
#pragma unroll
        for (int ak = 0; ak < 13; ++ak)
            acc[ak] = fmaf(A.y, wg0[13+ak], fmaf(A.x, wg0[ak], acc[ak]));
#pragma unroll
        for (int ak = 0; ak < 13; ++ak)
            acc[ak] = fmaf(A.w, wg1[13+ak], fmaf(A.z, wg1[ak], acc[ak]));
#pragma unroll
        for (int ak = 0; ak < 13; ++ak)
            acc[ak] = fmaf(B.y, wg2[13+ak], fmaf(B.x, wg2[ak], acc[ak]));
#pragma unroll
        for (int ak = 0; ak < 13; ++ak)
            acc[ak] = fmaf(B.w, wg3[13+ak], fmaf(B.z, wg3[ak], acc[ak]));
        A = An; B = Bn;
    }

    // ---- pass B (rare): rows r >= rstar use weight row mi0+1; float2 v
    // (d-pair 2g,2g+1 adjacent within quad g>>1 at sub-offset (g&1)*2).
    if (rstar < 13) {
        int ustar = 60*rstar;
        int tstar = (ustar >= 1) ? (ustar/13) : -1;
        if (tk == tstar) {
#pragma unroll
            for (int j = 0; j < 13; ++j) myC[j] = acc[j];
        }
        LDS_FENCE();
        if (tk >= tstar) {
#pragma unroll
            for (int j = 0; j < 13; ++j) acc[j] = 0.f;
            const float* __restrict__ wrow2 = weff6 + (size_t)(hk*14 + mi0 + 1)*WROW6;
            const float* __restrict__ vB = vgT + (size_t)b*BSTRIDE + tk*4;
#pragma unroll 1
            for (int g = 0; g < 128; ++g) {
                const float* wg = wrow2 + g*32;
                float2 v01 = *(const float2*)&vB[(g>>1)*256 + (g&1)*2];
#pragma unroll
                for (int ak = 0; ak < 13; ++ak)
                    acc[ak] = fmaf(v01.y, wg[13+ak], fmaf(v01.x, wg[ak], acc[ak]));
            }
        }
        if (tk == tstar) {
#pragma unroll
            for (int j = 0; j < 13; ++j)
                if (13*tk + j < ustar) acc[j] = myC[j];
        }
        LDS_FENCE();
    }

    // ---- softmax + AV, PHASE-BATCHED (R3 structure at JB=1 register budget).
    int dh = lane >> 2, cc = lane & 3;
    int hb13 = (hk*1024 + b)*13;
    if (tk < NT) {
#pragma unroll
        for (int j = 0; j < 13; ++j) myC[13*tk + j] = acc[j];
    }
    // vreg: v[b][d = hk*16+dh][t = cc+4j] in quad layout — global loads
    // issued before the fence so they overlap it.
    float vreg[15];
#pragma unroll
    for (int j = 0; j < 15; ++j)
        vreg[j] = vgT[(size_t)b*BSTRIDE + (size_t)(hk*4 + (dh>>2))*256
                      + (cc + 4*j)*4 + (dh&3)];
    LDS_FENCE();
    // phase 1: all 13 logits (13 beff2 loads + 13 LDS reads issued together)
    float lg[13];
    {
        int ak = lane % 13;              // ak_r = (r*60+lane)%13; 60%13 == 8
#pragma unroll
        for (int r = 0; r < 13; ++r) {
            int n = hb13 + r;
            int m = n >> 10;             // exact variant for this row
            int brow = (m*16 + hk)*13;
            float bv = beff2[brow + ak];
            lg[r] = (lane < NT) ? (myC[r*60 + lane] + bv) * 0.5f : -1e30f;
            ak += 8; if (ak >= 13) ak -= 13;
        }
    }
    // phase 2: 13 interleaved max chains -> exp (lg reused as ex)
#pragma unroll
    for (int r = 0; r < 13; ++r) {
        float mx = lg[r];
#pragma unroll
        for (int off = 32; off; off >>= 1) mx = fmaxf(mx, __shfl_xor(mx, off));
        lg[r] = (lane < NT) ? __expf(lg[r] - mx) : 0.f;
    }
    // phase 3: 13 interleaved sum chains -> attn -> LDS
#pragma unroll
    for (int r = 0; r < 13; ++r) {
        float s = lg[r];
#pragma unroll
        for (int off = 32; off; off >>= 1) s += __shfl_xor(s, off);
        if (lane < NT) myC[r*60 + lane] = lg[r] / s;
    }
    LDS_FENCE();
    // phase 4: AV for all 13 rows
#pragma unroll
    for (int r = 0; r < 13; ++r) {
        float a = 0.f;
#pragma unroll
        for (int j = 0; j < 15; ++j)
            a = fmaf(myC[r*60 + cc + 4*j], vreg[j], a);
        a += __shfl_xor(a, 1);
        a += __shfl_xor(a, 2);
        if (cc == 0) attout[(size_t)(hb13 + r)*NDH + dh] = a;
    }
}

// ---------------- K3: MLP + BN(eval) + ReLU + GroupNorm(16,128); 16 rows/block.
// R9-verified WIN (~75us): j = tid>>3, sl = tid&7 -> 8 lanes SHARE each W1
// row (float4 wave-load = 2 cachelines, was 64). f stride 260 keeps the 8
// distinct f[sl] reads conflict-free. GN octet at lane stride 8 -> shuffle
// offsets {8,16,32}. Math identical to original.
#define FS 260
__launch_bounds__(1024)
__global__ void ltae_mlp(const float* __restrict__ attout, const float* __restrict__ W1,
                         const float* __restrict__ b1, const float* __restrict__ bnw,
                         const float* __restrict__ bnb, const float* __restrict__ bnrm,
                         const float* __restrict__ bnrv, const float* __restrict__ gow,
                         const float* __restrict__ gob, float* __restrict__ out) {
    __shared__ float f[16*FS];   // 16,640 B
    int tid = threadIdx.x;
    int sl  = tid & 7;           // sample slot 0..7 (8 lanes share a W1 row)
    int j   = tid >> 3;          // output channel 0..127
    int base = blockIdx.x << 4;  // 16 sids per block; sid = a2*1024 + b2
    for (int k = tid; k < 16*NDM; k += 1024) {
        int s = k >> 8, c = k & 255;
        int sid2 = base + s;
        int aa = sid2 >> 10, bb = sid2 & 1023;
        int h2 = c >> 4, dhh = c & 15;
        f[s*FS + c] = attout[((size_t)((aa*16 + h2)*1024 + bb))*NDH + dhh];
    }
    __syncthreads();
    const float* fr0 = f + sl*FS;
    const float* fr1 = f + (sl+8)*FS;
    const float* w   = &W1[(size_t)j*NDM];
    float bj = b1[j];
    float acc0 = bj, acc1 = bj;
    for (int c = 0; c < NDM; c += 4) {
        float4 wv = *(const float4*)&w[c];      // 8 lanes/addr -> 2 lines/wave
        float4 f0 = *(const float4*)&fr0[c];    // 16B-aligned (FS*4 % 16 == 0)
        float4 f1 = *(const float4*)&fr1[c];
        acc0 += wv.x*f0.x + wv.y*f0.y + wv.z*f0.z + wv.w*f0.w;
        acc1 += wv.x*f1.x + wv.y*f1.y + wv.z*f1.z + wv.w*f1.w;
    }
    float rs = rsqrtf(bnrv[j] + 1e-5f);
    float sc = rs * bnw[j];
    float sh = bnb[j] - bnrm[j]*sc;
    float y0 = fmaxf(acc0*sc + sh, 0.f);
    float y1 = fmaxf(acc1*sc + sh, 0.f);
    float a1 = y0, b1s = y0*y0, a2 = y1, b2s = y1*y1;
#pragma unroll
    for (int off = 8; off < 64; off <<= 1) {    // GN octet at lane stride 8
        a1  += __shfl_xor(a1, off);
        b1s += __shfl_xor(b1s, off);
        a2  += __shfl_xor(a2, off);
        b2s += __shfl_xor(b2s, off);
    }
    float gw = gow[j], gb = gob[j];
    {
        float mean = a1 * 0.125f;
        float var  = b1s * 0.125f - mean*mean;
        float o = (y0 - mean) * rsqrtf(var + 1e-5f) * gw + gb;
        int sid = base + sl, aa = sid >> 10, bb = sid & 1023;
        out[((size_t)bb*NA + aa)*NMO + j] = o;
    }
    {
        float mean = a2 * 0.125f;
        float var  = b2s * 0.125f - mean*mean;
        float o = (y1 - mean) * rsqrtf(var + 1e-5f) * gw + gb;
        int sid = base + sl + 8, aa = sid >> 10, bb = sid & 1023;
        out[((size_t)bb*NA + aa)*NMO + j] = o;
    }
}

extern "C" void kernel_launch(void* const* d_in, const int* in_sizes, int n_in,
                              void* d_out, int out_size, void* d_ws, size_t ws_size,
                              hipStream_t stream) {
    const float* x    = (const float*)d_in[0];
    const float* Wc   = (const float*)d_in[1];
    const float* bc   = (const float*)d_in[2];
    const float* gnw  = (const float*)d_in[3];
    const float* gnb  = (const float*)d_in[4];
    const float* Q    = (const float*)d_in[5];
    const float* Wk   = (const float*)d_in[6];
    const float* bk   = (const float*)d_in[7];
    const float* W1   = (const float*)d_in[8];
    const float* b1   = (const float*)d_in[9];
    const float* bnw  = (const float*)d_in[10];
    const float* bnb  = (const float*)d_in[11];
    const float* bnrm = (const float*)d_in[12];
    const float* bnrv = (const float*)d_in[13];
    const float* gow  = (const float*)d_in[14];
    const float* gob  = (const float*)d_in[15];

    float* ws     = (float*)d_ws;
    float* weff6  = ws + OFF_WEFF;
    float* beff2  = ws + OFF_BEFF;
    float* vgT    = ws + OFF_VGT;
    float* attout = ws + OFF_ATT;
    float* outp   = (float*)d_out;

    hipLaunchKernelGGL(ltae_weff, dim3(NH*14), dim3(256), 0, stream, Q, Wk, bk, weff6, beff2);
    hipFuncSetAttribute((const void*)ltae_convgn,
                        hipFuncAttributeMaxDynamicSharedMemorySize, K1_LDS_BYTES);
    hipLaunchKernelGGL(ltae_convgn, dim3(NB), dim3(1024), K1_LDS_BYTES, stream,
                       x, Wc, bc, gnw, gnb, vgT);
    hipLaunchKernelGGL(ltae_attn, dim3(8192), dim3(128), 0, stream,
                       vgT, weff6, beff2, attout);
    hipLaunchKernelGGL(ltae_mlp, dim3(NA*NB/16), dim3(1024), 0, stream,
                       attout, W1, b1, bnw, bnb, bnrm, bnrv, gow, gob, outp);
}